// Round 7
// baseline (412.769 us; speedup 1.0000x reference)
//
#include <hip/hip_runtime.h>
#include <hip/hip_fp16.h>

#define Bn  4
#define Hn  256
#define Wn  256
#define Cn  16
#define NTn 9
#define HWn (Hn*Wn)
#define KF  129      // W/2 + 1
#define KFP 132      // padded k-row length (half2 units)
#define PI_F 3.14159265358979323846f

__device__ __forceinline__ int swz(int i) { return i ^ ((i >> 4) & 15); }

__device__ __forceinline__ void lds_fence() {
  __asm__ volatile("s_waitcnt lgkmcnt(0)" ::: "memory");
}

__device__ __forceinline__ float2 cmul(float2 a, float2 b) {
  return make_float2(a.x*b.x - a.y*b.y, a.x*b.y + a.y*b.x);
}

template<bool INV>
__device__ __forceinline__ void radix4(float2& x0, float2& x1, float2& x2, float2& x3) {
  float2 y0 = make_float2(x0.x + x2.x, x0.y + x2.y);
  float2 y1 = make_float2(x0.x - x2.x, x0.y - x2.y);
  float2 y2 = make_float2(x1.x + x3.x, x1.y + x3.y);
  float2 y3 = make_float2(x1.x - x3.x, x1.y - x3.y);
  x0 = make_float2(y0.x + y2.x, y0.y + y2.y);
  x2 = make_float2(y0.x - y2.x, y0.y - y2.y);
  if (!INV) {
    x1 = make_float2(y1.x + y3.y, y1.y - y3.x);   // y1 - i*y3
    x3 = make_float2(y1.x - y3.y, y1.y + y3.x);   // y1 + i*y3
  } else {
    x1 = make_float2(y1.x - y3.y, y1.y + y3.x);
    x3 = make_float2(y1.x + y3.y, y1.y - y3.x);
  }
}

struct Tw { float2 a1,a2,a3,b1,b2,b3,c1,c2,c3; };

template<bool INV>
__device__ __forceinline__ Tw make_tw(int lane) {
  const float sgn = INV ? 2.0f * PI_F : -2.0f * PI_F;
  Tw t; float sw, cw;
  __sincosf(sgn * (float)lane / 256.0f, &sw, &cw);
  t.a1 = make_float2(cw, sw); t.a2 = cmul(t.a1, t.a1); t.a3 = cmul(t.a2, t.a1);
  __sincosf(sgn * (float)(lane & 15) / 64.0f, &sw, &cw);
  t.b1 = make_float2(cw, sw); t.b2 = cmul(t.b1, t.b1); t.b3 = cmul(t.b2, t.b1);
  __sincosf(sgn * (float)(lane & 3) / 16.0f, &sw, &cw);
  t.c1 = make_float2(cw, sw); t.c2 = cmul(t.c1, t.c1); t.c3 = cmul(t.c2, t.c1);
  return t;
}

// Per-wave FFT-256, radix-4 DIF. Input v[a]=x[lane+64a]; natural-order output
// in scratch row s (read via s[swz(k)]). Wave-private s, no __syncthreads.
template<bool INV>
__device__ __forceinline__ void fft256(float2 v[4], float2* s, int lane, const Tw& t) {
  radix4<INV>(v[0], v[1], v[2], v[3]);
  v[1] = cmul(v[1], t.a1); v[2] = cmul(v[2], t.a2); v[3] = cmul(v[3], t.a3);
  s[swz(lane)]       = v[0];
  s[swz(lane + 64)]  = v[1];
  s[swz(lane + 128)] = v[2];
  s[swz(lane + 192)] = v[3];
  lds_fence();
  { int base = (lane >> 4) * 64 + (lane & 15);
    v[0] = s[swz(base)]; v[1] = s[swz(base + 16)];
    v[2] = s[swz(base + 32)]; v[3] = s[swz(base + 48)]; }
  lds_fence();
  radix4<INV>(v[0], v[1], v[2], v[3]);
  v[1] = cmul(v[1], t.b1); v[2] = cmul(v[2], t.b2); v[3] = cmul(v[3], t.b3);
  { int base = (lane >> 4) * 64 + (lane & 15);
    s[swz(base)]      = v[0];
    s[swz(base + 16)] = v[1];
    s[swz(base + 32)] = v[2];
    s[swz(base + 48)] = v[3]; }
  lds_fence();
  { int base = (lane >> 4) * 64 + ((lane >> 2) & 3) * 16 + (lane & 3);
    v[0] = s[swz(base)]; v[1] = s[swz(base + 4)];
    v[2] = s[swz(base + 8)]; v[3] = s[swz(base + 12)]; }
  lds_fence();
  radix4<INV>(v[0], v[1], v[2], v[3]);
  v[1] = cmul(v[1], t.c1); v[2] = cmul(v[2], t.c2); v[3] = cmul(v[3], t.c3);
  { int base = (lane & ~3) * 4 + (lane & 3);
    s[swz(base)]      = v[0];
    s[swz(base + 4)]  = v[1];
    s[swz(base + 8)]  = v[2];
    s[swz(base + 12)] = v[3]; }
  lds_fence();
  { int base = lane * 4;
    v[0] = s[swz(base)]; v[1] = s[swz(base + 1)];
    v[2] = s[swz(base + 2)]; v[3] = s[swz(base + 3)]; }
  lds_fence();
  radix4<INV>(v[0], v[1], v[2], v[3]);
  int dr = ((lane & 3) << 4) + (((lane >> 2) & 3) << 2) + (lane >> 4);
  s[swz(dr)]       = v[0];
  s[swz(dr + 64)]  = v[1];
  s[swz(dr + 128)] = v[2];
  s[swz(dr + 192)] = v[3];
  lds_fence();
}

// ---------------------------------------------------------------------------
// Warp index map + zero-init of the norm accumulators (block 0).
// ---------------------------------------------------------------------------
__global__ void k_idx(const float* __restrict__ T, int* __restrict__ idx,
                      float* __restrict__ nx2, float* __restrict__ ny2) {
#pragma clang fp contract(off)
  if (blockIdx.x == 0) {
    if (threadIdx.x < 64) nx2[threadIdx.x] = 0.f;
    for (int i = threadIdx.x; i < NTn * Bn * Cn; i += 256) ny2[i] = 0.f;
  }
  int g = blockIdx.x * blockDim.x + threadIdx.x;
  if (g >= NTn * HWn) return;
  int t = g / HWn, pix = g - t * HWn;
  int i = pix >> 8, j = pix & 255;
  const float* a = T + t * 8;
  float x = (float)j, y = (float)i;
  float kk = a[6] * x + a[7] * y + 1.0f;
  float xf = (a[0] * x + a[1] * y + a[2]) / kk;
  float yf = (a[3] * x + a[4] * y + a[5]) / kk;
  float xr = rintf(xf), yr = rintf(yf);
  bool valid = (xr >= 0.f) && (xr < (float)Wn) && (yr >= 0.f) && (yr < (float)Hn);
  idx[g] = valid ? ((int)yr * Wn + (int)xr) : -1;
}

// ---------------------------------------------------------------------------
// Row FFT of x, reading inp (B,H,W,C) directly: per spatial row, contiguous
// 16KB load + in-LDS channel transpose + 16 channel FFTs. Fused ||x||^2.
// Store k-contiguous: Fxt[(b*16+c)][i][k], 129 half2 per row.
// Block = (b, 4-row chunk). Grid = Bn*64.
// ---------------------------------------------------------------------------
__global__ void k_xrow(const float* __restrict__ inp, __half2* __restrict__ Fxt,
                       float* __restrict__ nx2) {
  __shared__ float ych[16][260];
  __shared__ float2 sb[4][264];
  __shared__ float4 redq[256];
  int w = threadIdx.x >> 6, lane = threadIdx.x & 63;
  int tid = threadIdx.x;
  Tw t = make_tw<false>(lane);
  int b = blockIdx.x >> 6;
  int i0 = (blockIdx.x & 63) << 2;
  float4 nxacc = make_float4(0.f, 0.f, 0.f, 0.f);
  for (int r = 0; r < 4; ++r) {
    int i = i0 + r;
    const float4* rowp = (const float4*)(inp + ((size_t)(b * Hn + i) * Wn) * Cn);
    int part = tid & 3;
#pragma unroll
    for (int p = 0; p < 4; ++p) {
      int j = (tid >> 2) + (p << 6);
      float4 v = rowp[j * 4 + part];
      nxacc.x += v.x * v.x; nxacc.y += v.y * v.y;
      nxacc.z += v.z * v.z; nxacc.w += v.w * v.w;
      ych[part * 4 + 0][j] = v.x; ych[part * 4 + 1][j] = v.y;
      ych[part * 4 + 2][j] = v.z; ych[part * 4 + 3][j] = v.w;
    }
    __syncthreads();
#pragma unroll
    for (int cc = 0; cc < 4; ++cc) {
      int c = w * 4 + cc;
      float2 v[4];
#pragma unroll
      for (int q = 0; q < 4; ++q) v[q] = make_float2(ych[c][lane + (q << 6)], 0.f);
      fft256<false>(v, sb[w], lane, t);
      __half2* Fp = Fxt + ((size_t)(b * Cn + c) * Hn + i) * KFP;
      Fp[lane]      = __float22half2_rn(sb[w][swz(lane)]);
      Fp[lane + 64] = __float22half2_rn(sb[w][swz(lane + 64)]);
      if (lane == 0) Fp[128] = __float22half2_rn(sb[w][swz(128)]);
    }
    __syncthreads();
  }
  redq[tid] = nxacc;
  __syncthreads();
  if (tid < 16) {
    int part = tid >> 2, q = tid & 3;
    float s = 0.f;
    for (int m = 0; m < 64; ++m) {
      float4 v = redq[m * 4 + part];
      s += (q == 0) ? v.x : (q == 1) ? v.y : (q == 2) ? v.z : v.w;
    }
    atomicAdd(nx2 + b * Cn + tid, s);
  }
}

// ---------------------------------------------------------------------------
// Column FFT of Fx with layout transform: Fxt[plane][i][k] -> Fxh[plane][k][r].
// Block = (plane, k-tile of 16). Cooperative tile load, 16 FFTs, r-contig store.
// ---------------------------------------------------------------------------
__global__ void k_colfft_x(const __half2* __restrict__ Fxt, __half2* __restrict__ Fxh) {
  __shared__ float2 tile[16][258];
  __shared__ float2 sb[4][264];
  int w = threadIdx.x >> 6, lane = threadIdx.x & 63;
  int tid = threadIdx.x;
  Tw t = make_tw<false>(lane);
  int plane = blockIdx.x / 9;
  int k0 = (blockIdx.x % 9) << 4;
  const __half2* Fp = Fxt + (size_t)plane * Hn * KFP;
  int kk = tid & 15;
  int kc = min(k0 + kk, 128);
#pragma unroll
  for (int pass = 0; pass < 16; ++pass) {
    int i = (tid >> 4) + (pass << 4);
    tile[kk][i] = __half22float2(Fp[(size_t)i * KFP + kc]);
  }
  __syncthreads();
#pragma unroll
  for (int m = 0; m < 4; ++m) {
    int k = k0 + w * 4 + m;
    if (k > 128) continue;
    float2 v[4];
#pragma unroll
    for (int q = 0; q < 4; ++q) v[q] = tile[w * 4 + m][lane + (q << 6)];
    fft256<false>(v, sb[w], lane, t);
    __half2* Op = Fxh + ((size_t)plane * KF + k) * Hn;
#pragma unroll
    for (int q = 0; q < 4; ++q) {
      int rr = lane + (q << 6);
      Op[rr] = __float22half2_rn(sb[w][swz(rr)]);
    }
  }
}

// ---------------------------------------------------------------------------
// Row FFT of warped y: gather from inp (B,H,W,C) — one 64B line per pixel
// serves ALL 16 channels. Fused ||y||^2. Store Yh[(tb*16+c)][i][k] k-contig.
// Block = (t,b, 4-row chunk). Grid = 36*64.
// ---------------------------------------------------------------------------
__global__ void k_yrow(const float* __restrict__ inp, const int* __restrict__ idx,
                       __half2* __restrict__ Yh, float* __restrict__ ny2) {
  __shared__ float ych[16][260];
  __shared__ int irow[256];
  __shared__ float2 sb[4][264];
  __shared__ float4 redq[256];
  int w = threadIdx.x >> 6, lane = threadIdx.x & 63;
  int tid = threadIdx.x;
  Tw t = make_tw<false>(lane);
  int tb = blockIdx.x >> 6;               // t*Bn + b
  int i0 = (blockIdx.x & 63) << 2;
  int b = tb & 3, tt = tb >> 2;
  const float4* ib = (const float4*)(inp + (size_t)b * HWn * Cn);
  const int* ixb = idx + (size_t)tt * HWn + (size_t)i0 * Wn;
  float4 nyacc = make_float4(0.f, 0.f, 0.f, 0.f);
  int part = tid & 3;
  for (int r = 0; r < 4; ++r) {
    irow[tid] = ixb[r * Wn + tid];
    __syncthreads();
#pragma unroll
    for (int p = 0; p < 4; ++p) {
      int j = (tid >> 2) + (p << 6);
      int id = irow[j];
      float4 v = (id >= 0) ? ib[id * 4 + part] : make_float4(0.f, 0.f, 0.f, 0.f);
      nyacc.x += v.x * v.x; nyacc.y += v.y * v.y;
      nyacc.z += v.z * v.z; nyacc.w += v.w * v.w;
      ych[part * 4 + 0][j] = v.x; ych[part * 4 + 1][j] = v.y;
      ych[part * 4 + 2][j] = v.z; ych[part * 4 + 3][j] = v.w;
    }
    __syncthreads();
#pragma unroll
    for (int cc = 0; cc < 4; ++cc) {
      int c = w * 4 + cc;
      float2 v[4];
#pragma unroll
      for (int q = 0; q < 4; ++q) v[q] = make_float2(ych[c][lane + (q << 6)], 0.f);
      fft256<false>(v, sb[w], lane, t);
      __half2* Yp = Yh + ((size_t)(tb * Cn + c) * Hn + i0 + r) * KFP;
      Yp[lane]      = __float22half2_rn(sb[w][swz(lane)]);
      Yp[lane + 64] = __float22half2_rn(sb[w][swz(lane + 64)]);
      if (lane == 0) Yp[128] = __float22half2_rn(sb[w][swz(128)]);
    }
    __syncthreads();
  }
  redq[tid] = nyacc;
  __syncthreads();
  if (tid < 16) {
    int pr = tid >> 2, q = tid & 3;
    float s = 0.f;
    for (int m = 0; m < 64; ++m) {
      float4 v = redq[m * 4 + pr];
      s += (q == 0) ? v.x : (q == 1) ? v.y : (q == 2) ? v.z : v.w;
    }
    atomicAdd(ny2 + tb * Cn + tid, s);
  }
}

// ---------------------------------------------------------------------------
// Per (t,b,k-tile of 16): column FFT of y over all 16 channels (cooperative
// tile loads from Yh[...][i][k]), Fx*conj(Fy)*scale accumulation, fused
// inverse FFT over row-frequency, single r-contiguous write of G[tb][k][j].
// ---------------------------------------------------------------------------
__global__ void k_ycol(const __half2* __restrict__ Yh, const __half2* __restrict__ Fxh,
                       const float* __restrict__ nx2, const float* __restrict__ ny2,
                       float2* __restrict__ G) {
  __shared__ float2 tile[16][258];
  __shared__ float2 sb[4][264];
  int w = threadIdx.x >> 6, lane = threadIdx.x & 63;
  int tid = threadIdx.x;
  Tw tf = make_tw<false>(lane);
  int tb = blockIdx.x / 9;                // t*Bn + b
  int k0 = (blockIdx.x % 9) << 4;
  int b = tb & 3;
  float2 acc[4][4];
#pragma unroll
  for (int m = 0; m < 4; ++m)
#pragma unroll
    for (int q = 0; q < 4; ++q) acc[m][q] = make_float2(0.f, 0.f);
  int kk = tid & 15;
  int kc = min(k0 + kk, 128);
  for (int c = 0; c < Cn; ++c) {
    const __half2* Yp = Yh + (size_t)(tb * Cn + c) * Hn * KFP;
#pragma unroll
    for (int pass = 0; pass < 16; ++pass) {
      int i = (tid >> 4) + (pass << 4);
      tile[kk][i] = __half22float2(Yp[(size_t)i * KFP + kc]);
    }
    __syncthreads();
    float nx = sqrtf(nx2[b * Cn + c]);
    float ny = sqrtf(ny2[tb * Cn + c]);
    float sc = 1.0f / ((float)Cn * (nx * ny + 1e-12f));
#pragma unroll
    for (int m = 0; m < 4; ++m) {
      int k = k0 + w * 4 + m;
      if (k > 128) continue;
      float2 v[4];
#pragma unroll
      for (int q = 0; q < 4; ++q) v[q] = tile[w * 4 + m][lane + (q << 6)];
      fft256<false>(v, sb[w], lane, tf);
      const __half2* Fxp = Fxh + ((size_t)(b * Cn + c) * KF + k) * Hn;
#pragma unroll
      for (int q = 0; q < 4; ++q) {
        int rr = lane + (q << 6);
        float2 fy = sb[w][swz(rr)];
        float2 fx = __half22float2(Fxp[rr]);
        acc[m][q].x += sc * (fx.x * fy.x + fx.y * fy.y);   // fx * conj(fy)
        acc[m][q].y += sc * (fx.y * fy.x - fx.x * fy.y);
      }
    }
    __syncthreads();
  }
  Tw ti = make_tw<true>(lane);
#pragma unroll
  for (int m = 0; m < 4; ++m) {
    int k = k0 + w * 4 + m;
    if (k > 128) continue;
    fft256<true>(acc[m], sb[w], lane, ti);
    float2* Gp = G + ((size_t)tb * KF + k) * Hn;
#pragma unroll
    for (int q = 0; q < 4; ++q) {
      int j = lane + (q << 6);
      Gp[j] = sb[w][swz(j)];
    }
  }
}

// ---------------------------------------------------------------------------
// Final pass: block = (b, 4 spatial rows) x ALL 9 transforms.
// Hermitian-extend + inverse row FFT per t, assemble rowbuf[row][j*9+t] in
// LDS, then fully-contiguous store of out[b,i,j,t].
// ---------------------------------------------------------------------------
__global__ void k_irow(const float2* __restrict__ G, float* __restrict__ out) {
  __shared__ float2 tile[4][132];
  __shared__ float rowbuf[4][Wn * NTn];
  __shared__ float2 sb[4][264];
  int w = threadIdx.x >> 6, lane = threadIdx.x & 63;
  Tw ti = make_tw<true>(lane);
  int b = blockIdx.x >> 6;
  int i0 = (blockIdx.x & 63) << 2;
  const float scale = 1.0f / ((float)Hn * (float)Wn);
  for (int t = 0; t < NTn; ++t) {
    int tb = t * Bn + b;
    {
      int ii = threadIdx.x & 3, kq = threadIdx.x >> 2;
      const float2* Gp = G + (size_t)tb * KF * Hn + i0 + ii;
#pragma unroll
      for (int kk0 = 0; kk0 < 128; kk0 += 64) {
        int kk = kk0 + kq;
        tile[ii][kk] = Gp[(size_t)kk * Hn];
      }
      if (threadIdx.x < 4) tile[ii][128] = Gp[(size_t)128 * Hn];
    }
    __syncthreads();
    float2 v[4];
#pragma unroll
    for (int q = 0; q < 4; ++q) {
      int k = lane + (q << 6);
      if (k <= 128) {
        v[q] = tile[w][k];
      } else {
        float2 z = tile[w][256 - k];
        v[q] = make_float2(z.x, -z.y);
      }
    }
    fft256<true>(v, sb[w], lane, ti);
#pragma unroll
    for (int q = 0; q < 4; ++q) {
      int j = lane + (q << 6);
      rowbuf[w][j * NTn + t] = sb[w][swz(j)].x * scale;
    }
    __syncthreads();
  }
  float* ob = out + ((size_t)(b * Hn + i0) * Wn) * NTn;
  for (int f = threadIdx.x; f < 4 * Wn * NTn; f += 256) {
    int r = f / (Wn * NTn), off = f - r * (Wn * NTn);
    ob[(size_t)r * Wn * NTn + off] = rowbuf[r][off];
  }
}

// ---------------------------------------------------------------------------
extern "C" void kernel_launch(void* const* d_in, const int* in_sizes, int n_in,
                              void* d_out, int out_size, void* d_ws, size_t ws_size,
                              hipStream_t stream) {
  const float* inp = (const float*)d_in[0];
  const float* T   = (const float*)d_in[1];
  float* out = (float*)d_out;
  char* ws = (char*)d_ws;

  size_t off = 0;
  int*     idx = (int*)(ws + off);     off += (size_t)NTn * HWn * sizeof(int);              // 2.4 MB
  float*   nx2 = (float*)(ws + off);   off += 256 * sizeof(float);
  float*   ny2 = (float*)(ws + off);   off += 768 * sizeof(float);
  __half2* Fxt = (__half2*)(ws + off); off += (size_t)Bn * Cn * Hn * KFP * sizeof(__half2); // 8.7 MB
  __half2* Fxh = (__half2*)(ws + off); off += (size_t)Bn * Cn * KF * Hn * sizeof(__half2);  // 8.5 MB
  float2*  G   = (float2*)(ws + off);  off += (size_t)NTn * Bn * KF * Hn * sizeof(float2);  // 9.5 MB
  __half2* Yh  = (__half2*)(ws + off); off += (size_t)NTn * Bn * Cn * Hn * KFP * sizeof(__half2); // 77.9 MB
  (void)off; (void)ws_size; (void)in_sizes; (void)n_in; (void)out_size;

  k_idx<<<(NTn * HWn + 255) / 256, 256, 0, stream>>>(T, idx, nx2, ny2);
  k_xrow<<<Bn * 64, 256, 0, stream>>>(inp, Fxt, nx2);
  k_colfft_x<<<Bn * Cn * 9, 256, 0, stream>>>(Fxt, Fxh);
  k_yrow<<<NTn * Bn * 64, 256, 0, stream>>>(inp, idx, Yh, ny2);
  k_ycol<<<NTn * Bn * 9, 256, 0, stream>>>(Yh, Fxh, nx2, ny2, G);
  k_irow<<<Bn * Hn / 4, 256, 0, stream>>>(G, out);
}

// Round 8
// 220.678 us; speedup vs baseline: 1.8705x; 1.8705x over previous
//
#include <hip/hip_runtime.h>
#include <hip/hip_fp16.h>

#define Bn  4
#define Hn  256
#define Wn  256
#define Cn  16
#define NTn 9
#define HWn (Hn*Wn)
#define KF  129      // W/2 + 1
#define PI_F 3.14159265358979323846f

__device__ __forceinline__ int swz(int i) { return i ^ ((i >> 4) & 15); }

__device__ __forceinline__ void lds_fence() {
  __asm__ volatile("s_waitcnt lgkmcnt(0)" ::: "memory");
}

__device__ __forceinline__ float2 cmul(float2 a, float2 b) {
  return make_float2(a.x*b.x - a.y*b.y, a.x*b.y + a.y*b.x);
}

template<bool INV>
__device__ __forceinline__ void radix4(float2& x0, float2& x1, float2& x2, float2& x3) {
  float2 y0 = make_float2(x0.x + x2.x, x0.y + x2.y);
  float2 y1 = make_float2(x0.x - x2.x, x0.y - x2.y);
  float2 y2 = make_float2(x1.x + x3.x, x1.y + x3.y);
  float2 y3 = make_float2(x1.x - x3.x, x1.y - x3.y);
  x0 = make_float2(y0.x + y2.x, y0.y + y2.y);
  x2 = make_float2(y0.x - y2.x, y0.y - y2.y);
  if (!INV) {
    x1 = make_float2(y1.x + y3.y, y1.y - y3.x);   // y1 - i*y3
    x3 = make_float2(y1.x - y3.y, y1.y + y3.x);   // y1 + i*y3
  } else {
    x1 = make_float2(y1.x - y3.y, y1.y + y3.x);
    x3 = make_float2(y1.x + y3.y, y1.y - y3.x);
  }
}

struct Tw { float2 a1,a2,a3,b1,b2,b3,c1,c2,c3; };

template<bool INV>
__device__ __forceinline__ Tw make_tw(int lane) {
  const float sgn = INV ? 2.0f * PI_F : -2.0f * PI_F;
  Tw t; float sw, cw;
  __sincosf(sgn * (float)lane / 256.0f, &sw, &cw);
  t.a1 = make_float2(cw, sw); t.a2 = cmul(t.a1, t.a1); t.a3 = cmul(t.a2, t.a1);
  __sincosf(sgn * (float)(lane & 15) / 64.0f, &sw, &cw);
  t.b1 = make_float2(cw, sw); t.b2 = cmul(t.b1, t.b1); t.b3 = cmul(t.b2, t.b1);
  __sincosf(sgn * (float)(lane & 3) / 16.0f, &sw, &cw);
  t.c1 = make_float2(cw, sw); t.c2 = cmul(t.c1, t.c1); t.c3 = cmul(t.c2, t.c1);
  return t;
}

// Per-wave FFT-256, radix-4 DIF. Input v[a]=x[lane+64a]; natural-order output
// in scratch row s (read via s[swz(k)]). Wave-private s, no __syncthreads.
template<bool INV>
__device__ __forceinline__ void fft256(float2 v[4], float2* s, int lane, const Tw& t) {
  radix4<INV>(v[0], v[1], v[2], v[3]);
  v[1] = cmul(v[1], t.a1); v[2] = cmul(v[2], t.a2); v[3] = cmul(v[3], t.a3);
  s[swz(lane)]       = v[0];
  s[swz(lane + 64)]  = v[1];
  s[swz(lane + 128)] = v[2];
  s[swz(lane + 192)] = v[3];
  lds_fence();
  { int base = (lane >> 4) * 64 + (lane & 15);
    v[0] = s[swz(base)]; v[1] = s[swz(base + 16)];
    v[2] = s[swz(base + 32)]; v[3] = s[swz(base + 48)]; }
  lds_fence();
  radix4<INV>(v[0], v[1], v[2], v[3]);
  v[1] = cmul(v[1], t.b1); v[2] = cmul(v[2], t.b2); v[3] = cmul(v[3], t.b3);
  { int base = (lane >> 4) * 64 + (lane & 15);
    s[swz(base)]      = v[0];
    s[swz(base + 16)] = v[1];
    s[swz(base + 32)] = v[2];
    s[swz(base + 48)] = v[3]; }
  lds_fence();
  { int base = (lane >> 4) * 64 + ((lane >> 2) & 3) * 16 + (lane & 3);
    v[0] = s[swz(base)]; v[1] = s[swz(base + 4)];
    v[2] = s[swz(base + 8)]; v[3] = s[swz(base + 12)]; }
  lds_fence();
  radix4<INV>(v[0], v[1], v[2], v[3]);
  v[1] = cmul(v[1], t.c1); v[2] = cmul(v[2], t.c2); v[3] = cmul(v[3], t.c3);
  { int base = (lane & ~3) * 4 + (lane & 3);
    s[swz(base)]      = v[0];
    s[swz(base + 4)]  = v[1];
    s[swz(base + 8)]  = v[2];
    s[swz(base + 12)] = v[3]; }
  lds_fence();
  { int base = lane * 4;
    v[0] = s[swz(base)]; v[1] = s[swz(base + 1)];
    v[2] = s[swz(base + 2)]; v[3] = s[swz(base + 3)]; }
  lds_fence();
  radix4<INV>(v[0], v[1], v[2], v[3]);
  int dr = ((lane & 3) << 4) + (((lane >> 2) & 3) << 2) + (lane >> 4);
  s[swz(dr)]       = v[0];
  s[swz(dr + 64)]  = v[1];
  s[swz(dr + 128)] = v[2];
  s[swz(dr + 192)] = v[3];
  lds_fence();
}

// ---------------------------------------------------------------------------
// Warp index map + zero-init of the norm accumulators (block 0).
// ---------------------------------------------------------------------------
__global__ void k_idx(const float* __restrict__ T, int* __restrict__ idx,
                      float* __restrict__ ny2) {
#pragma clang fp contract(off)
  if (blockIdx.x == 0) {
    for (int i = threadIdx.x; i < NTn * Bn * Cn; i += 256) ny2[i] = 0.f;
  }
  int g = blockIdx.x * blockDim.x + threadIdx.x;
  if (g >= NTn * HWn) return;
  int t = g / HWn, pix = g - t * HWn;
  int i = pix >> 8, j = pix & 255;
  const float* a = T + t * 8;
  float x = (float)j, y = (float)i;
  float kk = a[6] * x + a[7] * y + 1.0f;
  float xf = (a[0] * x + a[1] * y + a[2]) / kk;
  float yf = (a[3] * x + a[4] * y + a[5]) / kk;
  float xr = rintf(xf), yr = rintf(yf);
  bool valid = (xr >= 0.f) && (xr < (float)Wn) && (yr >= 0.f) && (yr < (float)Hn);
  idx[g] = valid ? ((int)yr * Wn + (int)xr) : -1;
}

// ---------------------------------------------------------------------------
// Row FFT of warped y (t=0 slab doubles as the x spectra — identity warp).
// Block = (tb, 4-channel group cg, 16 spatial rows). Gather one float4 per
// thread per pixel (full 64B line serves 16ch across the 4 cg blocks, L3-
// shared). Double-buffered staging; per-wave FFTs; spectra collected in LDS;
// final fully-coalesced 64B-granule transposed store to Yh[ch][k][i].
// Fused per-channel ||y||^2 accumulation.
// ---------------------------------------------------------------------------
__global__ void k_yrow(const float* __restrict__ inp, const int* __restrict__ idx,
                       __half2* __restrict__ Yh, float* __restrict__ ny2) {
  __shared__ float   ych[2][4][264];
  __shared__ float2  sb[4][264];
  __shared__ __half2 specbuf[4][16][132];
  __shared__ float4  redw[4];
  int tid = threadIdx.x, w = tid >> 6, lane = tid & 63;
  Tw t = make_tw<false>(lane);
  int chunk = blockIdx.x & 15, cg = (blockIdx.x >> 4) & 3, tb = blockIdx.x >> 6;
  int b = tb & 3, tt = tb >> 2;
  int i0 = chunk << 4;
  const float4* ib = (const float4*)(inp + (size_t)b * HWn * Cn);
  const int* ixb = idx + (size_t)tt * HWn + (size_t)i0 * Wn;
  int idxv[16];
#pragma unroll
  for (int r = 0; r < 16; ++r) idxv[r] = ixb[r * Wn + tid];
  float4 nyacc = make_float4(0.f, 0.f, 0.f, 0.f);
  float4 g;
  { int id = idxv[0];
    g = (id >= 0) ? ib[(size_t)id * 4 + cg] : make_float4(0.f, 0.f, 0.f, 0.f); }
  for (int r = 0; r < 16; ++r) {
    int cur = r & 1;
    ych[cur][0][tid] = g.x; ych[cur][1][tid] = g.y;
    ych[cur][2][tid] = g.z; ych[cur][3][tid] = g.w;
    nyacc.x += g.x * g.x; nyacc.y += g.y * g.y;
    nyacc.z += g.z * g.z; nyacc.w += g.w * g.w;
    __syncthreads();
    if (r + 1 < 16) {
      int id = idxv[r + 1];
      g = (id >= 0) ? ib[(size_t)id * 4 + cg] : make_float4(0.f, 0.f, 0.f, 0.f);
    }
    // wave w transforms channel cg*4+w of this row
    float2 v[4];
#pragma unroll
    for (int q = 0; q < 4; ++q) v[q] = make_float2(ych[cur][w][lane + (q << 6)], 0.f);
    fft256<false>(v, sb[w], lane, t);
    specbuf[w][r][lane]      = __float22half2_rn(sb[w][swz(lane)]);
    specbuf[w][r][lane + 64] = __float22half2_rn(sb[w][swz(lane + 64)]);
    if (lane == 0) specbuf[w][r][128] = __float22half2_rn(sb[w][swz(128)]);
  }
#pragma unroll
  for (int o = 32; o > 0; o >>= 1) {
    nyacc.x += __shfl_down(nyacc.x, o, 64);
    nyacc.y += __shfl_down(nyacc.y, o, 64);
    nyacc.z += __shfl_down(nyacc.z, o, 64);
    nyacc.w += __shfl_down(nyacc.w, o, 64);
  }
  if (lane == 0) redw[w] = nyacc;
  __syncthreads();   // publishes specbuf + redw
  if (tid == 0) {
    float4 s = make_float4(redw[0].x + redw[1].x + redw[2].x + redw[3].x,
                           redw[0].y + redw[1].y + redw[2].y + redw[3].y,
                           redw[0].z + redw[1].z + redw[2].z + redw[3].z,
                           redw[0].w + redw[1].w + redw[2].w + redw[3].w);
    atomicAdd(ny2 + tb * Cn + cg * 4 + 0, s.x);
    atomicAdd(ny2 + tb * Cn + cg * 4 + 1, s.y);
    atomicAdd(ny2 + tb * Cn + cg * 4 + 2, s.z);
    atomicAdd(ny2 + tb * Cn + cg * 4 + 3, s.w);
  }
  int ii = tid & 15, kq = tid >> 4;
#pragma unroll
  for (int p = 0; p < 9; ++p) {
    int k = p * 16 + kq;
    if (k <= 128) {
#pragma unroll
      for (int cc = 0; cc < 4; ++cc) {
        Yh[((size_t)(tb * Cn + cg * 4 + cc) * KF + k) * Hn + i0 + ii] = specbuf[cc][ii][k];
      }
    }
  }
}

// ---------------------------------------------------------------------------
// Column FFT of the x spectra: reads the t=0 slab of Yh (contiguous rows),
// writes Fxh[(b*16+c)*KF + k][r] (contiguous). Wave per item, no barriers.
// ---------------------------------------------------------------------------
__global__ void k_colfft_fx(const __half2* __restrict__ Yh, __half2* __restrict__ Fxh) {
  __shared__ float2 sb[4][264];
  int w = threadIdx.x >> 6, lane = threadIdx.x & 63;
  Tw t = make_tw<false>(lane);
  int item = blockIdx.x * 4 + w;            // (b*16+c)*KF + k  (t=0 slab is Yh's start)
  const __half2* Sp = Yh + (size_t)item * Hn;
  float2 v[4];
#pragma unroll
  for (int q = 0; q < 4; ++q) v[q] = __half22float2(Sp[lane + (q << 6)]);
  fft256<false>(v, sb[w], lane, t);
  __half2* Op = Fxh + (size_t)item * Hn;
#pragma unroll
  for (int q = 0; q < 4; ++q) {
    int j = lane + (q << 6);
    Op[j] = __float22half2_rn(sb[w][swz(j)]);
  }
}

// ---------------------------------------------------------------------------
// Per (t,b,k): column FFT of y over 16 channels + Fx*conj(Fy)*scale accum,
// fused inverse FFT over row-frequency, one contiguous write of G[tb][k][j].
// Wave per item, zero barriers, contiguous reads.
// ---------------------------------------------------------------------------
__global__ void k_ycol(const __half2* __restrict__ Yh, const __half2* __restrict__ Fxh,
                       const float* __restrict__ ny2, float2* __restrict__ G) {
  __shared__ float2 sb[4][264];
  int w = threadIdx.x >> 6, lane = threadIdx.x & 63;
  float2* s = sb[w];
  Tw tf = make_tw<false>(lane);
  int item = blockIdx.x * 4 + w;            // tb*KF + k
  int k = item % KF, tb = item / KF;
  int b = tb & 3;
  float2 acc[4];
#pragma unroll
  for (int q = 0; q < 4; ++q) acc[q] = make_float2(0.f, 0.f);
  for (int c = 0; c < Cn; ++c) {
    const __half2* Yp = Yh + ((size_t)(tb * Cn + c) * KF + k) * Hn;
    float2 v[4];
#pragma unroll
    for (int q = 0; q < 4; ++q) v[q] = __half22float2(Yp[lane + (q << 6)]);
    fft256<false>(v, s, lane, tf);
    float nx = sqrtf(ny2[b * Cn + c]);      // t=0 slab == x norms
    float ny = sqrtf(ny2[tb * Cn + c]);
    float sc = 1.0f / ((float)Cn * (nx * ny + 1e-12f));
    const __half2* Fxp = Fxh + ((size_t)(b * Cn + c) * KF + k) * Hn;
#pragma unroll
    for (int q = 0; q < 4; ++q) {
      int rr = lane + (q << 6);
      float2 fy = s[swz(rr)];
      float2 fx = __half22float2(Fxp[rr]);
      acc[q].x += sc * (fx.x * fy.x + fx.y * fy.y);   // fx * conj(fy)
      acc[q].y += sc * (fx.y * fy.x - fx.x * fy.y);
    }
  }
  Tw ti = make_tw<true>(lane);
  fft256<true>(acc, s, lane, ti);
  float2* Gp = G + (size_t)item * Hn;
#pragma unroll
  for (int q = 0; q < 4; ++q) {
    int j = lane + (q << 6);
    Gp[j] = s[swz(j)];
  }
}

// ---------------------------------------------------------------------------
// Final pass: block = (b, 4 spatial rows) x ALL 9 transforms.
// Hermitian-extend + inverse row FFT per t, assemble rowbuf[row][j*9+t] in
// LDS, then fully-contiguous store of out[b,i,j,t].
// ---------------------------------------------------------------------------
__global__ void k_irow(const float2* __restrict__ G, float* __restrict__ out) {
  __shared__ float2 tile[4][132];
  __shared__ float rowbuf[4][Wn * NTn];
  __shared__ float2 sb[4][264];
  int w = threadIdx.x >> 6, lane = threadIdx.x & 63;
  Tw ti = make_tw<true>(lane);
  int b = blockIdx.x >> 6;
  int i0 = (blockIdx.x & 63) << 2;
  const float scale = 1.0f / ((float)Hn * (float)Wn);
  for (int t = 0; t < NTn; ++t) {
    int tb = t * Bn + b;
    {
      int ii = threadIdx.x & 3, kq = threadIdx.x >> 2;
      const float2* Gp = G + (size_t)tb * KF * Hn + i0 + ii;
#pragma unroll
      for (int kk0 = 0; kk0 < 128; kk0 += 64) {
        int kk = kk0 + kq;
        tile[ii][kk] = Gp[(size_t)kk * Hn];
      }
      if (threadIdx.x < 4) tile[ii][128] = Gp[(size_t)128 * Hn];
    }
    __syncthreads();
    float2 v[4];
#pragma unroll
    for (int q = 0; q < 4; ++q) {
      int k = lane + (q << 6);
      if (k <= 128) {
        v[q] = tile[w][k];
      } else {
        float2 z = tile[w][256 - k];
        v[q] = make_float2(z.x, -z.y);
      }
    }
    fft256<true>(v, sb[w], lane, ti);
#pragma unroll
    for (int q = 0; q < 4; ++q) {
      int j = lane + (q << 6);
      rowbuf[w][j * NTn + t] = sb[w][swz(j)].x * scale;
    }
    __syncthreads();
  }
  float* ob = out + ((size_t)(b * Hn + i0) * Wn) * NTn;
  for (int f = threadIdx.x; f < 4 * Wn * NTn; f += 256) {
    int r = f / (Wn * NTn), off = f - r * (Wn * NTn);
    ob[(size_t)r * Wn * NTn + off] = rowbuf[r][off];
  }
}

// ---------------------------------------------------------------------------
extern "C" void kernel_launch(void* const* d_in, const int* in_sizes, int n_in,
                              void* d_out, int out_size, void* d_ws, size_t ws_size,
                              hipStream_t stream) {
  const float* inp = (const float*)d_in[0];
  const float* T   = (const float*)d_in[1];
  float* out = (float*)d_out;
  char* ws = (char*)d_ws;

  size_t off = 0;
  int*     idx = (int*)(ws + off);     off += (size_t)NTn * HWn * sizeof(int);               // 2.4 MB
  float*   ny2 = (float*)(ws + off);   off += 1024 * sizeof(float);
  __half2* Fxh = (__half2*)(ws + off); off += (size_t)Bn * Cn * KF * Hn * sizeof(__half2);   // 8.5 MB
  float2*  G   = (float2*)(ws + off);  off += (size_t)NTn * Bn * KF * Hn * sizeof(float2);   // 9.5 MB
  __half2* Yh  = (__half2*)(ws + off); off += (size_t)NTn * Bn * Cn * KF * Hn * sizeof(__half2); // 76 MB
  (void)off; (void)ws_size; (void)in_sizes; (void)n_in; (void)out_size;

  k_idx<<<(NTn * HWn + 255) / 256, 256, 0, stream>>>(T, idx, ny2);
  k_yrow<<<NTn * Bn * 4 * 16, 256, 0, stream>>>(inp, idx, Yh, ny2);
  k_colfft_fx<<<Bn * Cn * KF / 4, 256, 0, stream>>>(Yh, Fxh);
  k_ycol<<<NTn * Bn * KF / 4, 256, 0, stream>>>(Yh, Fxh, ny2, G);
  k_irow<<<Bn * Hn / 4, 256, 0, stream>>>(G, out);
}

// Round 9
// 213.499 us; speedup vs baseline: 1.9334x; 1.0336x over previous
//
#include <hip/hip_runtime.h>
#include <hip/hip_fp16.h>

#define Bn  4
#define Hn  256
#define Wn  256
#define Cn  16
#define NTn 9
#define HWn (Hn*Wn)
#define KF  129      // W/2 + 1
#define PI_F 3.14159265358979323846f

__device__ __forceinline__ int swz(int i) { return i ^ ((i >> 4) & 15); }

__device__ __forceinline__ void lds_fence() {
  __asm__ volatile("s_waitcnt lgkmcnt(0)" ::: "memory");
}

__device__ __forceinline__ float2 cmul(float2 a, float2 b) {
  return make_float2(a.x*b.x - a.y*b.y, a.x*b.y + a.y*b.x);
}

template<bool INV>
__device__ __forceinline__ void radix4(float2& x0, float2& x1, float2& x2, float2& x3) {
  float2 y0 = make_float2(x0.x + x2.x, x0.y + x2.y);
  float2 y1 = make_float2(x0.x - x2.x, x0.y - x2.y);
  float2 y2 = make_float2(x1.x + x3.x, x1.y + x3.y);
  float2 y3 = make_float2(x1.x - x3.x, x1.y - x3.y);
  x0 = make_float2(y0.x + y2.x, y0.y + y2.y);
  x2 = make_float2(y0.x - y2.x, y0.y - y2.y);
  if (!INV) {
    x1 = make_float2(y1.x + y3.y, y1.y - y3.x);   // y1 - i*y3
    x3 = make_float2(y1.x - y3.y, y1.y + y3.x);   // y1 + i*y3
  } else {
    x1 = make_float2(y1.x - y3.y, y1.y + y3.x);
    x3 = make_float2(y1.x + y3.y, y1.y - y3.x);
  }
}

struct Tw { float2 a1,a2,a3,b1,b2,b3,c1,c2,c3; };

template<bool INV>
__device__ __forceinline__ Tw make_tw(int lane) {
  const float sgn = INV ? 2.0f * PI_F : -2.0f * PI_F;
  Tw t; float sw, cw;
  __sincosf(sgn * (float)lane / 256.0f, &sw, &cw);
  t.a1 = make_float2(cw, sw); t.a2 = cmul(t.a1, t.a1); t.a3 = cmul(t.a2, t.a1);
  __sincosf(sgn * (float)(lane & 15) / 64.0f, &sw, &cw);
  t.b1 = make_float2(cw, sw); t.b2 = cmul(t.b1, t.b1); t.b3 = cmul(t.b2, t.b1);
  __sincosf(sgn * (float)(lane & 3) / 16.0f, &sw, &cw);
  t.c1 = make_float2(cw, sw); t.c2 = cmul(t.c1, t.c1); t.c3 = cmul(t.c2, t.c1);
  return t;
}

// Per-wave FFT-256, radix-4 DIF. Input v[a]=x[lane+64a]; natural-order output
// in scratch row s (read via s[swz(k)]). Wave-private s, no __syncthreads.
template<bool INV>
__device__ __forceinline__ void fft256(float2 v[4], float2* s, int lane, const Tw& t) {
  radix4<INV>(v[0], v[1], v[2], v[3]);
  v[1] = cmul(v[1], t.a1); v[2] = cmul(v[2], t.a2); v[3] = cmul(v[3], t.a3);
  s[swz(lane)]       = v[0];
  s[swz(lane + 64)]  = v[1];
  s[swz(lane + 128)] = v[2];
  s[swz(lane + 192)] = v[3];
  lds_fence();
  { int base = (lane >> 4) * 64 + (lane & 15);
    v[0] = s[swz(base)]; v[1] = s[swz(base + 16)];
    v[2] = s[swz(base + 32)]; v[3] = s[swz(base + 48)]; }
  lds_fence();
  radix4<INV>(v[0], v[1], v[2], v[3]);
  v[1] = cmul(v[1], t.b1); v[2] = cmul(v[2], t.b2); v[3] = cmul(v[3], t.b3);
  { int base = (lane >> 4) * 64 + (lane & 15);
    s[swz(base)]      = v[0];
    s[swz(base + 16)] = v[1];
    s[swz(base + 32)] = v[2];
    s[swz(base + 48)] = v[3]; }
  lds_fence();
  { int base = (lane >> 4) * 64 + ((lane >> 2) & 3) * 16 + (lane & 3);
    v[0] = s[swz(base)]; v[1] = s[swz(base + 4)];
    v[2] = s[swz(base + 8)]; v[3] = s[swz(base + 12)]; }
  lds_fence();
  radix4<INV>(v[0], v[1], v[2], v[3]);
  v[1] = cmul(v[1], t.c1); v[2] = cmul(v[2], t.c2); v[3] = cmul(v[3], t.c3);
  { int base = (lane & ~3) * 4 + (lane & 3);
    s[swz(base)]      = v[0];
    s[swz(base + 4)]  = v[1];
    s[swz(base + 8)]  = v[2];
    s[swz(base + 12)] = v[3]; }
  lds_fence();
  { int base = lane * 4;
    v[0] = s[swz(base)]; v[1] = s[swz(base + 1)];
    v[2] = s[swz(base + 2)]; v[3] = s[swz(base + 3)]; }
  lds_fence();
  radix4<INV>(v[0], v[1], v[2], v[3]);
  int dr = ((lane & 3) << 4) + (((lane >> 2) & 3) << 2) + (lane >> 4);
  s[swz(dr)]       = v[0];
  s[swz(dr + 64)]  = v[1];
  s[swz(dr + 128)] = v[2];
  s[swz(dr + 192)] = v[3];
  lds_fence();
}

// Inline projective warp map (matches reference: fp-contract off, rintf).
__device__ __forceinline__ int warp_id(float a0, float a1, float a2, float a3,
                                       float a4, float a5, float a6, float a7,
                                       int col, int row) {
#pragma clang fp contract(off)
  float x = (float)col, y = (float)row;
  float kk = a6 * x + a7 * y + 1.0f;
  float xf = (a0 * x + a1 * y + a2) / kk;
  float yf = (a3 * x + a4 * y + a5) / kk;
  float xr = rintf(xf), yr = rintf(yf);
  bool valid = (xr >= 0.f) && (xr < 256.f) && (yr >= 0.f) && (yr < 256.f);
  return valid ? ((int)yr * Wn + (int)xr) : -1;
}

// ---------------------------------------------------------------------------
__global__ void k_zero(float* __restrict__ ny2) {
  int t = threadIdx.x;
  for (int i = t; i < NTn * Bn * Cn; i += 256) ny2[i] = 0.f;
}

// ---------------------------------------------------------------------------
// Row FFT of warped y (t=0 slab == x spectra, identity warp).
// Block = (tb, cg channel-quad, 16-row chunk). Real-PAIR packing: rows
// (2r,2r+1) share one complex FFT, Hermitian-unpacked. Inline warp map
// (no idx buffer). specbuf stages 8 rows, flushed twice with 32B granules.
// Fused per-channel ||y||^2.
// ---------------------------------------------------------------------------
__global__ __launch_bounds__(256) void k_yrow(const float* __restrict__ inp,
                                              const float* __restrict__ T,
                                              __half2* __restrict__ Yh,
                                              float* __restrict__ ny2) {
  __shared__ float   ych[2][4][264];
  __shared__ float2  sb[4][264];
  __shared__ __half2 specbuf[4][8][132];
  __shared__ float4  redw[4];
  int tid = threadIdx.x, w = tid >> 6, lane = tid & 63;
  Tw t = make_tw<false>(lane);
  int chunk = blockIdx.x & 15, cg = (blockIdx.x >> 4) & 3, tb = blockIdx.x >> 6;
  int b = tb & 3, tt = tb >> 2;
  int i0 = chunk << 4;
  const float4* ib = (const float4*)(inp + (size_t)b * HWn * Cn);
  float a0, a1, a2, a3, a4, a5, a6, a7;
  { const float* a = T + tt * 8;
    a0=a[0]; a1=a[1]; a2=a[2]; a3=a[3]; a4=a[4]; a5=a[5]; a6=a[6]; a7=a[7]; }
  float4 nyacc = make_float4(0.f, 0.f, 0.f, 0.f);
  float4 g0, g1;
  {
    int id0 = warp_id(a0,a1,a2,a3,a4,a5,a6,a7, tid, i0);
    int id1 = warp_id(a0,a1,a2,a3,a4,a5,a6,a7, tid, i0 + 1);
    g0 = (id0 >= 0) ? ib[(size_t)id0 * 4 + cg] : make_float4(0.f,0.f,0.f,0.f);
    g1 = (id1 >= 0) ? ib[(size_t)id1 * 4 + cg] : make_float4(0.f,0.f,0.f,0.f);
  }
  for (int pr = 0; pr < 8; ++pr) {
    if (pr == 4) {
      __syncthreads();
      // flush rows 0..7 (spatial i0..i0+7)
      int ii = tid & 7, kq = tid >> 3;
#pragma unroll
      for (int p = 0; p < 5; ++p) {
        int k = p * 32 + kq;
        if (k <= 128) {
#pragma unroll
          for (int cc = 0; cc < 4; ++cc)
            Yh[((size_t)(tb * Cn + cg * 4 + cc) * KF + k) * Hn + i0 + ii] = specbuf[cc][ii][k];
        }
      }
    }
    __syncthreads();
    ych[0][0][tid] = g0.x; ych[0][1][tid] = g0.y; ych[0][2][tid] = g0.z; ych[0][3][tid] = g0.w;
    ych[1][0][tid] = g1.x; ych[1][1][tid] = g1.y; ych[1][2][tid] = g1.z; ych[1][3][tid] = g1.w;
    nyacc.x += g0.x*g0.x + g1.x*g1.x; nyacc.y += g0.y*g0.y + g1.y*g1.y;
    nyacc.z += g0.z*g0.z + g1.z*g1.z; nyacc.w += g0.w*g0.w + g1.w*g1.w;
    __syncthreads();
    if (pr < 7) {
      int r0 = i0 + 2 * (pr + 1);
      int id0 = warp_id(a0,a1,a2,a3,a4,a5,a6,a7, tid, r0);
      int id1 = warp_id(a0,a1,a2,a3,a4,a5,a6,a7, tid, r0 + 1);
      g0 = (id0 >= 0) ? ib[(size_t)id0 * 4 + cg] : make_float4(0.f,0.f,0.f,0.f);
      g1 = (id1 >= 0) ? ib[(size_t)id1 * 4 + cg] : make_float4(0.f,0.f,0.f,0.f);
    }
    // wave w: channel cg*4+w, rows (2pr, 2pr+1) packed as re+im
    float2 v[4];
#pragma unroll
    for (int q = 0; q < 4; ++q) {
      int j = lane + (q << 6);
      v[q] = make_float2(ych[0][w][j], ych[1][w][j]);
    }
    fft256<false>(v, sb[w], lane, t);
    int lr0 = (2 * pr) & 7, lr1 = lr0 + 1;
#pragma unroll
    for (int q = 0; q < 2; ++q) {
      int k = lane + (q << 6);
      float2 Z  = sb[w][swz(k)];
      float2 Zc = sb[w][swz((256 - k) & 255)];
      float2 Fa = make_float2(0.5f * (Z.x + Zc.x), 0.5f * (Z.y - Zc.y));
      float2 Fb = make_float2(0.5f * (Z.y + Zc.y), 0.5f * (Zc.x - Z.x));
      specbuf[w][lr0][k] = __float22half2_rn(Fa);
      specbuf[w][lr1][k] = __float22half2_rn(Fb);
    }
    if (lane == 0) {
      float2 Z = sb[w][swz(128)];
      specbuf[w][lr0][128] = __float22half2_rn(make_float2(Z.x, 0.f));
      specbuf[w][lr1][128] = __float22half2_rn(make_float2(Z.y, 0.f));
    }
  }
#pragma unroll
  for (int o = 32; o > 0; o >>= 1) {
    nyacc.x += __shfl_down(nyacc.x, o, 64);
    nyacc.y += __shfl_down(nyacc.y, o, 64);
    nyacc.z += __shfl_down(nyacc.z, o, 64);
    nyacc.w += __shfl_down(nyacc.w, o, 64);
  }
  if (lane == 0) redw[w] = nyacc;
  __syncthreads();
  {
    // flush rows 8..15
    int ii = tid & 7, kq = tid >> 3;
#pragma unroll
    for (int p = 0; p < 5; ++p) {
      int k = p * 32 + kq;
      if (k <= 128) {
#pragma unroll
        for (int cc = 0; cc < 4; ++cc)
          Yh[((size_t)(tb * Cn + cg * 4 + cc) * KF + k) * Hn + i0 + 8 + ii] = specbuf[cc][ii][k];
      }
    }
  }
  if (tid == 0) {
    float4 s = make_float4(redw[0].x + redw[1].x + redw[2].x + redw[3].x,
                           redw[0].y + redw[1].y + redw[2].y + redw[3].y,
                           redw[0].z + redw[1].z + redw[2].z + redw[3].z,
                           redw[0].w + redw[1].w + redw[2].w + redw[3].w);
    atomicAdd(ny2 + tb * Cn + cg * 4 + 0, s.x);
    atomicAdd(ny2 + tb * Cn + cg * 4 + 1, s.y);
    atomicAdd(ny2 + tb * Cn + cg * 4 + 2, s.z);
    atomicAdd(ny2 + tb * Cn + cg * 4 + 3, s.w);
  }
}

// ---------------------------------------------------------------------------
// Column FFT of x spectra: reads t=0 slab of Yh (contiguous), writes Fxh
// (contiguous). Wave per item, no barriers.
// ---------------------------------------------------------------------------
__global__ void k_colfft_fx(const __half2* __restrict__ Yh, __half2* __restrict__ Fxh) {
  __shared__ float2 sb[4][264];
  int w = threadIdx.x >> 6, lane = threadIdx.x & 63;
  Tw t = make_tw<false>(lane);
  int item = blockIdx.x * 4 + w;            // (b*16+c)*KF + k
  const __half2* Sp = Yh + (size_t)item * Hn;
  float2 v[4];
#pragma unroll
  for (int q = 0; q < 4; ++q) v[q] = __half22float2(Sp[lane + (q << 6)]);
  fft256<false>(v, sb[w], lane, t);
  __half2* Op = Fxh + (size_t)item * Hn;
#pragma unroll
  for (int q = 0; q < 4; ++q) {
    int j = lane + (q << 6);
    Op[j] = __float22half2_rn(sb[w][swz(j)]);
  }
}

// ---------------------------------------------------------------------------
// Per (t,b,k): column FFT over 16 channels + Fx*conj(Fy)*scale accumulation,
// fused inverse FFT over row-frequency, contiguous write of G[tb][k][i].
// Wave per item, zero barriers.
// ---------------------------------------------------------------------------
__global__ void k_ycol(const __half2* __restrict__ Yh, const __half2* __restrict__ Fxh,
                       const float* __restrict__ ny2, float2* __restrict__ G) {
  __shared__ float2 sb[4][264];
  int w = threadIdx.x >> 6, lane = threadIdx.x & 63;
  float2* s = sb[w];
  Tw tf = make_tw<false>(lane);
  int item = blockIdx.x * 4 + w;            // tb*KF + k
  int k = item % KF, tb = item / KF;
  int b = tb & 3;
  float2 acc[4];
#pragma unroll
  for (int q = 0; q < 4; ++q) acc[q] = make_float2(0.f, 0.f);
  for (int c = 0; c < Cn; ++c) {
    const __half2* Yp = Yh + ((size_t)(tb * Cn + c) * KF + k) * Hn;
    float2 v[4];
#pragma unroll
    for (int q = 0; q < 4; ++q) v[q] = __half22float2(Yp[lane + (q << 6)]);
    fft256<false>(v, s, lane, tf);
    float nx = sqrtf(ny2[b * Cn + c]);      // t=0 slab == x norms
    float ny = sqrtf(ny2[tb * Cn + c]);
    float sc = 1.0f / ((float)Cn * (nx * ny + 1e-12f));
    const __half2* Fxp = Fxh + ((size_t)(b * Cn + c) * KF + k) * Hn;
#pragma unroll
    for (int q = 0; q < 4; ++q) {
      int rr = lane + (q << 6);
      float2 fy = s[swz(rr)];
      float2 fx = __half22float2(Fxp[rr]);
      acc[q].x += sc * (fx.x * fy.x + fx.y * fy.y);   // fx * conj(fy)
      acc[q].y += sc * (fx.y * fy.x - fx.x * fy.y);
    }
  }
  Tw ti = make_tw<true>(lane);
  fft256<true>(acc, s, lane, ti);
  float2* Gp = G + (size_t)item * Hn;
#pragma unroll
  for (int q = 0; q < 4; ++q) {
    int j = lane + (q << 6);
    Gp[j] = s[swz(j)];
  }
}

// ---------------------------------------------------------------------------
// Final pass: block = (b, spatial row i), 5 waves. Wave tp handles t-pair
// (2tp, 2tp+1): Hermitian-extend both spectra, pack A + iB, ONE inverse FFT,
// re/im are the two t's correlations. Assemble rowbuf[j*9+t], contiguous store.
// ---------------------------------------------------------------------------
__global__ __launch_bounds__(320) void k_irow(const float2* __restrict__ G,
                                              float* __restrict__ out) {
  __shared__ float2 tile[5][2][132];
  __shared__ float2 sb[5][264];
  __shared__ float rowbuf[Wn * NTn];
  int tid = threadIdx.x, w = tid >> 6, lane = tid & 63;
  Tw ti = make_tw<true>(lane);
  int b = blockIdx.x >> 8, i = blockIdx.x & 255;
  const float scale = 1.0f / ((float)Hn * (float)Wn);
  int t1 = 2 * w, t2 = t1 + 1;
  {
    const float2* Gp1 = G + ((size_t)(t1 * Bn + b) * KF) * Hn + i;
    for (int k = lane; k < KF; k += 64) tile[w][0][k] = Gp1[(size_t)k * Hn];
    if (t2 < NTn) {
      const float2* Gp2 = G + ((size_t)(t2 * Bn + b) * KF) * Hn + i;
      for (int k = lane; k < KF; k += 64) tile[w][1][k] = Gp2[(size_t)k * Hn];
    }
  }
  lds_fence();   // tile[w] is wave-private
  float2 v[4];
#pragma unroll
  for (int q = 0; q < 4; ++q) {
    int k = lane + (q << 6);
    float2 a, bb;
    if (k <= 128) a = tile[w][0][k];
    else { float2 z = tile[w][0][256 - k]; a = make_float2(z.x, -z.y); }
    if (t2 < NTn) {
      if (k <= 128) bb = tile[w][1][k];
      else { float2 z = tile[w][1][256 - k]; bb = make_float2(z.x, -z.y); }
    } else bb = make_float2(0.f, 0.f);
    v[q] = make_float2(a.x - bb.y, a.y + bb.x);   // A + i*B
  }
  fft256<true>(v, sb[w], lane, ti);
#pragma unroll
  for (int q = 0; q < 4; ++q) {
    int j = lane + (q << 6);
    float2 r = sb[w][swz(j)];
    rowbuf[j * NTn + t1] = r.x * scale;
    if (t2 < NTn) rowbuf[j * NTn + t2] = r.y * scale;
  }
  __syncthreads();
  float* ob = out + ((size_t)(b * Hn + i) * Wn) * NTn;
  for (int f = tid; f < Wn * NTn; f += 320) ob[f] = rowbuf[f];
}

// ---------------------------------------------------------------------------
extern "C" void kernel_launch(void* const* d_in, const int* in_sizes, int n_in,
                              void* d_out, int out_size, void* d_ws, size_t ws_size,
                              hipStream_t stream) {
  const float* inp = (const float*)d_in[0];
  const float* T   = (const float*)d_in[1];
  float* out = (float*)d_out;
  char* ws = (char*)d_ws;

  size_t off = 0;
  float*   ny2 = (float*)(ws + off);   off += 1024 * sizeof(float);
  __half2* Fxh = (__half2*)(ws + off); off += (size_t)Bn * Cn * KF * Hn * sizeof(__half2);   // 8.5 MB
  float2*  G   = (float2*)(ws + off);  off += (size_t)NTn * Bn * KF * Hn * sizeof(float2);   // 9.5 MB
  __half2* Yh  = (__half2*)(ws + off); off += (size_t)NTn * Bn * Cn * KF * Hn * sizeof(__half2); // 76 MB
  (void)off; (void)ws_size; (void)in_sizes; (void)n_in; (void)out_size;

  k_zero<<<1, 256, 0, stream>>>(ny2);
  k_yrow<<<NTn * Bn * 4 * 16, 256, 0, stream>>>(inp, T, Yh, ny2);
  k_colfft_fx<<<Bn * Cn * KF / 4, 256, 0, stream>>>(Yh, Fxh);
  k_ycol<<<NTn * Bn * KF / 4, 256, 0, stream>>>(Yh, Fxh, ny2, G);
  k_irow<<<Bn * Hn, 320, 0, stream>>>(G, out);
}